// Round 1
// baseline (216.558 us; speedup 1.0000x reference)
//
#include <hip/hip_runtime.h>
#include <math.h>

// FourierKNOConv2d: x[8,32,256,256] f32, kernel[2,1,32,32,32,2] f32, r scalar.
// out[8,32,256,256] f32.
//   kP: Kp = (kr + i ki)^r                                  [2,32,32,32] c64
//   kA: Z1[row,w] = sum_x X[row,x] e^{-2pi i w x/256}, w<32  (x<->256-x symmetry)
//   kB: Z2[bc,t,w] = sum_y Z1[bc,y,w] e^{-2pi i h(t) y/256}, h(t)=t<32?t:192+t
//       (split y into two halves -> z2a + z2b, summed in kC)
//   kC: G = idft32_ch( dft32_ch(z2a+z2b) * Kp ) / 8192
//   kD: T[bc,y,w] = sum_t G[bc,t,w] e^{+2pi i h(t) y/256}
//   kE: out[row,x] = C(x)-S(x), out[row,256-x] = C(x)+S(x)  (x-symmetry; col 128 special)
// ws map (24.5 MB, stream-ordered reuse):
//   z1  @0..16M    (kA w, kB r)
//   z2a @16..20M, z2b @20..24M (kB w, kC r)
//   kp  @24..24.5M (kP w, kC r)
//   g   @0..4M     (kC w, kD r; over dead z1)
//   tb  @4..20M    (kD w, kE r; over dead z1/z2a)

#define TWO_PI 6.28318530717958647692f

__global__ __launch_bounds__(256) void kP(const float* __restrict__ kin,
                                          const float* __restrict__ rp,
                                          float2* __restrict__ kp) {
  const int i = blockIdx.x * 256 + threadIdx.x;  // < 65536
  const float r = rp[0];
  const float kr = kin[2 * i], ki = kin[2 * i + 1];
  const float m2 = fmaf(kr, kr, ki * ki);
  float2 o = make_float2(0.f, 0.f);
  if (m2 > 0.f) {
    const float lm = 0.5f * logf(m2);
    const float ang = atan2f(ki, kr);
    const float mag = expf(r * lm);
    float s, c;
    sincosf(r * ang, &s, &c);
    o = make_float2(mag * c, mag * s);
  }
  kp[i] = o;
}

// kA: 2048 blocks; block = 32 rows. LDS [x][r] stride 36.
// Pass1 stage transposed; pass2 replace x/(256-x) with u=a+b (slot x), v=a-b (slot 256-x).
// Thread = (wg=tid&15 -> w in {wg, wg+16}, rq=tid>>4 -> rows 2rq, 2rq+1):
// 2 freqs x 2 rows per thread. Each ds_read_b64 of u/v feeds 2 freqs' FMAs
// (vs 1 before) -> LDS issue-pipe load halved (b64 not b128), useful-FMA
// fraction up. 127-iter dual-phasor loop + edge terms x=0,128.
__global__ __launch_bounds__(256) void kA(const float* __restrict__ x,
                                          float2* __restrict__ z1) {
  __shared__ float xs[256 * 36];  // 36 KB
  const int tid = threadIdx.x;
  const long row0 = (long)blockIdx.x * 32;
  const float* xg = x + row0 * 256;
#pragma unroll 4
  for (int r = 0; r < 32; ++r) xs[tid * 36 + r] = xg[r * 256 + tid];
  __syncthreads();
  for (int i = tid; i < 127 * 32; i += 256) {
    const int xi = 1 + (i >> 5), r = i & 31;
    const float a = xs[xi * 36 + r], b = xs[(256 - xi) * 36 + r];
    xs[xi * 36 + r] = a + b;          // u
    xs[(256 - xi) * 36 + r] = a - b;  // v
  }
  __syncthreads();
  const int wg = tid & 15;         // w = wg and wg + 16
  const int r0 = (tid >> 4) << 1;  // rows r0, r0+1
  // edge terms: Re += X(0) + (-1)^w X(128); parity of wg == parity of wg+16
  const float sgn = (wg & 1) ? -1.f : 1.f;
  const float2 x0 = *(const float2*)(xs + r0);
  const float2 x128 = *(const float2*)(xs + 128 * 36 + r0);
  float Cr00 = fmaf(sgn, x128.x, x0.x), Cr01 = fmaf(sgn, x128.y, x0.y);
  float Cr10 = Cr00, Cr11 = Cr01;
  float Ci00 = 0, Ci01 = 0, Ci10 = 0, Ci11 = 0;
  float s0, c0, s1, c1;
  sincosf(TWO_PI * (float)wg / 256.0f, &s0, &c0);
  sincosf(TWO_PI * (float)(wg + 16) / 256.0f, &s1, &c1);
  float pc0 = c0, ps0 = s0;  // phasor for w=wg at x=1
  float pc1 = c1, ps1 = s1;  // phasor for w=wg+16 at x=1
  const float* pu = xs + 36 + r0;
  const float* pv = xs + 255 * 36 + r0;
  for (int xx = 1; xx < 128; ++xx) {
    const float2 u = *(const float2*)pu;
    const float2 v = *(const float2*)pv;
    pu += 36; pv -= 36;
    Cr00 = fmaf(u.x, pc0, Cr00); Ci00 = fmaf(-v.x, ps0, Ci00);
    Cr01 = fmaf(u.y, pc0, Cr01); Ci01 = fmaf(-v.y, ps0, Ci01);
    Cr10 = fmaf(u.x, pc1, Cr10); Ci10 = fmaf(-v.x, ps1, Ci10);
    Cr11 = fmaf(u.y, pc1, Cr11); Ci11 = fmaf(-v.y, ps1, Ci11);
    float tn = fmaf(pc0, c0, -ps0 * s0);
    ps0 = fmaf(pc0, s0, ps0 * c0);
    pc0 = tn;
    tn = fmaf(pc1, c1, -ps1 * s1);
    ps1 = fmaf(pc1, s1, ps1 * c1);
    pc1 = tn;
  }
  float2* o = z1 + (row0 + r0) * 32 + wg;
  o[0]  = make_float2(Cr00, Ci00);  // row r0,   w=wg
  o[16] = make_float2(Cr10, Ci10);  // row r0,   w=wg+16
  o[32] = make_float2(Cr01, Ci01);  // row r0+1, w=wg
  o[48] = make_float2(Cr11, Ci11);  // row r0+1, w=wg+16
}

// kB: 512 blocks = (bc, yh). Thread = (t=tid>>2, wq=tid&3): 8 w per thread.
// Partial over 128 y -> z2p[yh]. Phasor start (-1)^(h*yh), step e^{-2pi i h/256}.
__global__ __launch_bounds__(256) void kB(const float2* __restrict__ z1,
                                          float2* __restrict__ z2p) {
  __shared__ float2 zs[128 * 32];  // 32 KB, [y][w]
  const int bc = blockIdx.x >> 1, yh = blockIdx.x & 1;
  const float2* src = z1 + (long)bc * 8192 + yh * 4096;
  for (int i = threadIdx.x; i < 4096; i += 256) zs[i] = src[i];
  __syncthreads();
  const int t = threadIdx.x >> 2, wq = threadIdx.x & 3;
  const int h = (t < 32) ? t : (192 + t);
  float sr, cr;
  sincosf(-TWO_PI * (float)h / 256.0f, &sr, &cr);
  float pc = (yh && (t & 1)) ? -1.f : 1.f, ps = 0.f;
  float ar[8], ai[8];
#pragma unroll
  for (int k = 0; k < 8; ++k) { ar[k] = 0.f; ai[k] = 0.f; }
  const float* zb = (const float*)zs + wq * 16;
  for (int y = 0; y < 128; ++y) {
    const float4* zf = (const float4*)(zb + y * 64);
#pragma unroll
    for (int k = 0; k < 4; ++k) {
      const float4 q = zf[k];
      ar[2 * k]     = fmaf(q.x, pc, fmaf(-q.y, ps, ar[2 * k]));
      ai[2 * k]     = fmaf(q.x, ps, fmaf( q.y, pc, ai[2 * k]));
      ar[2 * k + 1] = fmaf(q.z, pc, fmaf(-q.w, ps, ar[2 * k + 1]));
      ai[2 * k + 1] = fmaf(q.z, ps, fmaf( q.w, pc, ai[2 * k + 1]));
    }
    const float tn = fmaf(pc, cr, -ps * sr);
    ps = fmaf(pc, sr, ps * cr);
    pc = tn;
  }
  float4* dst = (float4*)(z2p + (long)yh * 524288 + (long)bc * 2048 + t * 32 + wq * 8);
#pragma unroll
  for (int k = 0; k < 4; ++k)
    dst[k] = make_float4(ar[2 * k], ai[2 * k], ar[2 * k + 1], ai[2 * k + 1]);
}

// kC: 1024 blocks; block = 16 modes (same b,t; 16 w). Sums z2a+z2b at load.
__global__ __launch_bounds__(256) void kC(const float2* __restrict__ z2a,
                                          const float2* __restrict__ z2b,
                                          const float2* __restrict__ kp,
                                          float2* __restrict__ g) {
  __shared__ float2 z2s[16 * 33];
  __shared__ float2 fk[16 * 33];
  __shared__ float2 tw[32];
  const int tid = threadIdx.x;
  if (tid < 32) {
    float s, c;
    sincosf(-TWO_PI * (float)tid / 32.0f, &s, &c);
    tw[tid] = make_float2(c, s);
  }
  const int m0 = blockIdx.x * 16;
  const int b = m0 >> 11;
  const int twi = m0 & 2047;
  const int t = twi >> 5;
  const int w0 = twi & 31;
  const int s_ = t >> 5, tm = t & 31;
  for (int i = tid; i < 512; i += 256) {
    const int ci = i >> 4, wj = i & 15;
    const long idx = ((long)(b * 32 + ci)) * 2048 + t * 32 + w0 + wj;
    const float2 va = z2a[idx], vb = z2b[idx];
    z2s[wj * 33 + ci] = make_float2(va.x + vb.x, va.y + vb.y);
  }
  __syncthreads();
  const int m = tid & 15;
  const int p = tid >> 4;
  const int cf0 = 2 * p, cf1 = 2 * p + 1;
  {
    float f0r = 0, f0i = 0, f1r = 0, f1i = 0;
    int i0 = 0, i1 = 0;
#pragma unroll 8
    for (int ci = 0; ci < 32; ++ci) {
      const float2 z = z2s[m * 33 + ci];
      const float2 t0 = tw[i0]; i0 = (i0 + cf0) & 31;
      const float2 t1 = tw[i1]; i1 = (i1 + cf1) & 31;
      f0r = fmaf(z.x, t0.x, fmaf(-z.y, t0.y, f0r));
      f0i = fmaf(z.x, t0.y, fmaf( z.y, t0.x, f0i));
      f1r = fmaf(z.x, t1.x, fmaf(-z.y, t1.y, f1r));
      f1i = fmaf(z.x, t1.y, fmaf( z.y, t1.x, f1i));
    }
    const float2 k0 = kp[((s_ * 32 + cf0) * 32 + tm) * 32 + w0 + m];
    const float2 k1 = kp[((s_ * 32 + cf1) * 32 + tm) * 32 + w0 + m];
    fk[m * 33 + cf0] = make_float2(f0r * k0.x - f0i * k0.y, f0r * k0.y + f0i * k0.x);
    fk[m * 33 + cf1] = make_float2(f1r * k1.x - f1i * k1.y, f1r * k1.y + f1i * k1.x);
  }
  __syncthreads();
  {
    float g0r = 0, g0i = 0, g1r = 0, g1i = 0;
    int i0 = 0, i1 = 0;
    const int co0 = 2 * p, co1 = 2 * p + 1;
#pragma unroll 8
    for (int cf = 0; cf < 32; ++cf) {
      const float2 f = fk[m * 33 + cf];
      const float2 t0 = tw[i0]; i0 = (i0 + co0) & 31;
      const float2 t1 = tw[i1]; i1 = (i1 + co1) & 31;
      g0r = fmaf(f.x, t0.x, fmaf( f.y, t0.y, g0r));
      g0i = fmaf(f.y, t0.x, fmaf(-f.x, t0.y, g0i));
      g1r = fmaf(f.x, t1.x, fmaf( f.y, t1.y, g1r));
      g1i = fmaf(f.y, t1.x, fmaf(-f.x, t1.y, g1i));
    }
    const float SC = 1.0f / 8192.0f;
    g[((long)(b * 32 + co0)) * 2048 + t * 32 + w0 + m] = make_float2(g0r * SC, g0i * SC);
    g[((long)(b * 32 + co1)) * 2048 + t * 32 + w0 + m] = make_float2(g1r * SC, g1i * SC);
  }
}

// kD: 512 blocks = (bc, yh). Thread = (yl=tid>>1, wh=tid&1): 16 w per thread.
__global__ __launch_bounds__(256) void kD(const float2* __restrict__ g,
                                          float2* __restrict__ tb) {
  __shared__ float2 gs[64 * 32];  // 16 KB
  const int bc = blockIdx.x >> 1, yh = blockIdx.x & 1;
  const float2* src = g + (long)bc * 2048;
  for (int i = threadIdx.x; i < 2048; i += 256) gs[i] = src[i];
  __syncthreads();
  const int yl = threadIdx.x >> 1, wh = threadIdx.x & 1;
  const int y = yh * 128 + yl;
  float s1, c1;
  sincosf(TWO_PI * (float)y / 256.0f, &s1, &c1);  // step e^{+2pi i y/256}
  float Tr[16], Ti[16];
#pragma unroll
  for (int k = 0; k < 16; ++k) { Tr[k] = 0.f; Ti[k] = 0.f; }
  float pc = 1.f, ps = 0.f;
  const float* gb = (const float*)gs + wh * 32;
  for (int t = 0; t < 64; ++t) {
    if (t == 32) {
      float s2, c2;
      sincosf(TWO_PI * (float)((224 * y) & 255) / 256.0f, &s2, &c2);
      pc = c2; ps = s2;
    }
    const float4* gf = (const float4*)(gb + t * 64);
#pragma unroll
    for (int k = 0; k < 8; ++k) {
      const float4 q = gf[k];
      Tr[2 * k]     = fmaf(q.x, pc, fmaf(-q.y, ps, Tr[2 * k]));
      Ti[2 * k]     = fmaf(q.x, ps, fmaf( q.y, pc, Ti[2 * k]));
      Tr[2 * k + 1] = fmaf(q.z, pc, fmaf(-q.w, ps, Tr[2 * k + 1]));
      Ti[2 * k + 1] = fmaf(q.z, ps, fmaf( q.w, pc, Ti[2 * k + 1]));
    }
    const float tn = fmaf(pc, c1, -ps * s1);
    ps = fmaf(pc, s1, ps * c1);
    pc = tn;
  }
  float4* dst = (float4*)(tb + (long)bc * 8192 + y * 32 + wh * 16);
#pragma unroll
  for (int k = 0; k < 8; ++k)
    dst[k] = make_float4(Tr[2 * k], Ti[2 * k], Tr[2 * k + 1], Ti[2 * k + 1]);
}

// kE: 2048 blocks; block = 32 rows. Thread = (xq=tid&31 -> x in {xq+32m, m<4},
// rh=tid>>5 -> rows 4rh..4rh+3). 4 x-phasors per thread (steps related by
// x e^{i pi m/4}) reuse each tst read for 4 x-values -> LDS instr / 4.
// out(x)=C-S, out((256-x)&255)=C+S; col 128 via divergent tail (first 32 lanes).
// T staged [w][r] stride 34 float2, scale folded (1/256 for w=0, 2/256 else).
__global__ __launch_bounds__(256) void kE(const float2* __restrict__ tb,
                                          float* __restrict__ out) {
  __shared__ float2 tst[32 * 34];  // 8.5 KB
  const long row0 = (long)blockIdx.x * 32;
  const int tid = threadIdx.x;
  for (int i = tid; i < 1024; i += 256) {
    const int w = i & 31, r = i >> 5;
    const float2 v = tb[(row0 + r) * 32 + w];
    const float sc = w ? (2.0f / 256.0f) : (1.0f / 256.0f);
    tst[w * 34 + r] = make_float2(v.x * sc, v.y * sc);
  }
  __syncthreads();
  const int xq = tid & 31;  // x = xq + 32*m
  const int rh = tid >> 5;  // rows rh*4 .. rh*4+3
  float sb, cb;
  sincosf(TWO_PI * (float)xq / 256.0f, &sb, &cb);
  // step_m = (cb + i sb) * e^{i pi m / 4}
  const float RT = 0.70710678118654752440f;
  const float stc1 = RT * (cb - sb), sts1 = RT * (cb + sb);
  const float stc[4] = {cb, stc1, -sb, -sts1};
  const float sts[4] = {sb, sts1, cb, stc1};
  float C[4][4], S[4][4];
#pragma unroll
  for (int m = 0; m < 4; ++m)
#pragma unroll
    for (int j = 0; j < 4; ++j) { C[m][j] = 0.f; S[m][j] = 0.f; }
  float pc[4] = {1.f, 1.f, 1.f, 1.f}, ps[4] = {0.f, 0.f, 0.f, 0.f};
  const float* tbse = (const float*)tst + rh * 8;
  for (int w = 0; w < 32; ++w) {
    const float4 q0 = *(const float4*)(tbse + w * 68);      // rows 4rh, 4rh+1
    const float4 q1 = *(const float4*)(tbse + w * 68 + 4);  // rows 4rh+2, 4rh+3
#pragma unroll
    for (int m = 0; m < 4; ++m) {
      C[m][0] = fmaf(q0.x, pc[m], C[m][0]);
      S[m][0] = fmaf(q0.y, ps[m], S[m][0]);
      C[m][1] = fmaf(q0.z, pc[m], C[m][1]);
      S[m][1] = fmaf(q0.w, ps[m], S[m][1]);
      C[m][2] = fmaf(q1.x, pc[m], C[m][2]);
      S[m][2] = fmaf(q1.y, ps[m], S[m][2]);
      C[m][3] = fmaf(q1.z, pc[m], C[m][3]);
      S[m][3] = fmaf(q1.w, ps[m], S[m][3]);
      const float tn = fmaf(pc[m], stc[m], -ps[m] * sts[m]);
      ps[m] = fmaf(pc[m], sts[m], ps[m] * stc[m]);
      pc[m] = tn;
    }
  }
#pragma unroll
  for (int m = 0; m < 4; ++m) {
    const int xx = xq + 32 * m;
#pragma unroll
    for (int j = 0; j < 4; ++j) {
      const long row = row0 + rh * 4 + j;
      out[row * 256 + xx] = C[m][j] - S[m][j];
      out[row * 256 + ((256 - xx) & 255)] = C[m][j] + S[m][j];
    }
  }
  if (tid < 32) {  // column x=128: sum (-1)^w a_w
    float ae = 0.f, ao = 0.f;
#pragma unroll
    for (int k = 0; k < 16; ++k) {
      ae += tst[(2 * k) * 34 + tid].x;
      ao += tst[(2 * k + 1) * 34 + tid].x;
    }
    out[(row0 + tid) * 256 + 128] = ae - ao;
  }
}

extern "C" void kernel_launch(void* const* d_in, const int* in_sizes, int n_in,
                              void* d_out, int out_size, void* d_ws, size_t ws_size,
                              hipStream_t stream) {
  const float* x = (const float*)d_in[0];
  const float* kin = (const float*)d_in[1];
  const float* rp = (const float*)d_in[2];
  float* out = (float*)d_out;
  char* ws = (char*)d_ws;

  float2* z1  = (float2*)(ws);                   // 0..16M
  float2* z2a = (float2*)(ws + (16ull << 20));   // 16..24M (z2b = z2a+524288)
  float2* kp  = (float2*)(ws + (24ull << 20));   // 24..24.5M
  float2* g   = (float2*)(ws);                   // 0..4M (over dead z1)
  float2* tb  = (float2*)(ws + (4ull << 20));    // 4..20M (over dead z1/z2a)

  kP<<<256, 256, 0, stream>>>(kin, rp, kp);
  kA<<<2048, 256, 0, stream>>>(x, z1);
  kB<<<512, 256, 0, stream>>>(z1, z2a);
  kC<<<1024, 256, 0, stream>>>(z2a, z2a + 524288, kp, g);
  kD<<<512, 256, 0, stream>>>(g, tb);
  kE<<<2048, 256, 0, stream>>>(tb, out);
}

// Round 2
// 211.080 us; speedup vs baseline: 1.0260x; 1.0260x over previous
//
#include <hip/hip_runtime.h>
#include <math.h>

// FourierKNOConv2d: x[8,32,256,256] f32, kernel[2,1,32,32,32,2] f32, r scalar.
// out[8,32,256,256] f32.
//   kP: Kp = (kr + i ki)^r                                  [2,32,32,32] c64
//   kA: Z1[row,w] = sum_x X[row,x] e^{-2pi i w x/256}, w<32  (x<->256-x symmetry)
//   kB: Z2[bc,t,w] = sum_y Z1[bc,y,w] e^{-2pi i h(t) y/256}, h(t)=t<32?t:192+t
//       (split y into two halves -> z2a + z2b, summed in kC)
//   kC: G = idft32_ch( dft32_ch(z2a+z2b) * Kp ) / 8192
//   kD: T[bc,y,w] = sum_t G[bc,t,w] e^{+2pi i h(t) y/256}
//   kE: out[row,x] = C(x)-S(x), out[row,256-x] = C(x)+S(x)  (x-symmetry; col 128 special)
// ws map (24.5 MB, stream-ordered reuse):
//   z1  @0..16M    (kA w, kB r)
//   z2a @16..20M, z2b @20..24M (kB w, kC r)
//   kp  @24..24.5M (kP w, kC r)
//   g   @0..4M     (kC w, kD r; over dead z1)
//   tb  @4..20M    (kD w, kE r; over dead z1/z2a)

#define TWO_PI 6.28318530717958647692f

__global__ __launch_bounds__(256) void kP(const float* __restrict__ kin,
                                          const float* __restrict__ rp,
                                          float2* __restrict__ kp) {
  const int i = blockIdx.x * 256 + threadIdx.x;  // < 65536
  const float r = rp[0];
  const float kr = kin[2 * i], ki = kin[2 * i + 1];
  const float m2 = fmaf(kr, kr, ki * ki);
  float2 o = make_float2(0.f, 0.f);
  if (m2 > 0.f) {
    const float lm = 0.5f * logf(m2);
    const float ang = atan2f(ki, kr);
    const float mag = expf(r * lm);
    float s, c;
    sincosf(r * ang, &s, &c);
    o = make_float2(mag * c, mag * s);
  }
  kp[i] = o;
}

// kA: 2048 blocks; block = 32 rows. LDS 32 KB EXACTLY (5 blocks/CU = 20 waves,
// vs 4 blocks at the old padded 36 KB) via rotate-swizzle:
//   word idx(x,r) = x*32 + ((r + 4x) & 31)
// b128 quads (r0 multiple of 4) stay contiguous under the rotate (slot is a
// multiple of 4, max 28 -> never wraps mid-quad). Staging writes are 8-way
// bank conflicts — identical to the old stride-36 layout.
// Thread = (w=tid&31, rq=tid>>5): 1 freq x 4 rows (best VALU:FMA ratio).
// Main loop unrolled in batches of 8 x-values; swizzle offsets precomputed in
// uo[8] (v-side offsets are the same table reversed: (r0-4j)&31 = uo[(8-j)&7]),
// so per iteration only 2 address v_adds + 2 ds_read_b128 + 8 FMA + 3 phasor.
__global__ __launch_bounds__(256) void kA(const float* __restrict__ x,
                                          float2* __restrict__ z1) {
  __shared__ float xs[8192];  // 32 KB
  const int tid = threadIdx.x;
  const long row0 = (long)blockIdx.x * 32;
  const float* xg = x + row0 * 256;
  {
    const int rot = (4 * tid) & 31;
    float* col = xs + tid * 32;
#pragma unroll
    for (int r = 0; r < 32; ++r) col[(r + rot) & 31] = xg[r * 256 + tid];
  }
  __syncthreads();
  for (int i = tid; i < 127 * 32; i += 256) {
    const int xi = 1 + (i >> 5), r = i & 31;
    const int ai = (xi << 5) + ((r + 4 * xi) & 31);
    const int bi = ((256 - xi) << 5) + ((r - 4 * xi) & 31);
    const float a = xs[ai], b = xs[bi];
    xs[ai] = a + b;          // u
    xs[bi] = a - b;          // v
  }
  __syncthreads();
  const int w = tid & 31;
  const int r0 = (tid >> 5) << 2;  // rows r0..r0+3
  int uo[8];                       // byte offsets of swizzled quad, period 8 in x
#pragma unroll
  for (int j = 0; j < 8; ++j) uo[j] = ((r0 + 4 * j) & 31) << 2;
  // edge terms: Re += X(0) + (-1)^w X(128)   (idx(0,r)=r, idx(128,r)=4096+r)
  const float sgn = (w & 1) ? -1.f : 1.f;
  const float4 x0 = *(const float4*)(xs + r0);
  const float4 x128 = *(const float4*)(xs + (128 << 5) + r0);
  float Cr0 = fmaf(sgn, x128.x, x0.x), Cr1 = fmaf(sgn, x128.y, x0.y);
  float Cr2 = fmaf(sgn, x128.z, x0.z), Cr3 = fmaf(sgn, x128.w, x0.w);
  float Ci0 = 0, Ci1 = 0, Ci2 = 0, Ci3 = 0;
  float s1, c1;
  sincosf(TWO_PI * (float)w / 256.0f, &s1, &c1);
  float pc = c1, ps = s1;  // phasor at x=1 (positive angle; sign applied on Im)
  const char* const xsb = (const char*)xs;
#define KA_BODY(UPTR, VPTR)                                        \
  {                                                                \
    const float4 u = *(const float4*)(UPTR);                       \
    const float4 v = *(const float4*)(VPTR);                       \
    Cr0 = fmaf(u.x, pc, Cr0); Ci0 = fmaf(-v.x, ps, Ci0);           \
    Cr1 = fmaf(u.y, pc, Cr1); Ci1 = fmaf(-v.y, ps, Ci1);           \
    Cr2 = fmaf(u.z, pc, Cr2); Ci2 = fmaf(-v.z, ps, Ci2);           \
    Cr3 = fmaf(u.w, pc, Cr3); Ci3 = fmaf(-v.w, ps, Ci3);           \
    const float tn = fmaf(pc, c1, -ps * s1);                       \
    ps = fmaf(pc, s1, ps * c1);                                    \
    pc = tn;                                                       \
  }
  {  // batch 0: xx = 1..7  (v at x'=256-j -> base 249*128 + (7-j)*128)
    const char* ub = xsb;
    const char* vb = xsb + 249 * 128;
#pragma unroll
    for (int j = 1; j < 8; ++j)
      KA_BODY(ub + j * 128 + uo[j], vb + (7 - j) * 128 + uo[8 - j])
  }
  for (int xb = 8; xb <= 120; xb += 8) {  // xx = 8..127
    const char* ub = xsb + xb * 128;
    const char* vb = xsb + (249 - xb) * 128;
#pragma unroll
    for (int j = 0; j < 8; ++j)
      KA_BODY(ub + j * 128 + uo[j], vb + (7 - j) * 128 + uo[(8 - j) & 7])
  }
#undef KA_BODY
  float2* o = z1 + (row0 + r0) * 32 + w;
  o[0]  = make_float2(Cr0, Ci0);
  o[32] = make_float2(Cr1, Ci1);
  o[64] = make_float2(Cr2, Ci2);
  o[96] = make_float2(Cr3, Ci3);
}

// kB: 512 blocks = (bc, yh). Thread = (t=tid>>2, wq=tid&3): 8 w per thread.
// Partial over 128 y -> z2p[yh]. Phasor start (-1)^(h*yh), step e^{-2pi i h/256}.
__global__ __launch_bounds__(256) void kB(const float2* __restrict__ z1,
                                          float2* __restrict__ z2p) {
  __shared__ float2 zs[128 * 32];  // 32 KB, [y][w]
  const int bc = blockIdx.x >> 1, yh = blockIdx.x & 1;
  const float2* src = z1 + (long)bc * 8192 + yh * 4096;
  for (int i = threadIdx.x; i < 4096; i += 256) zs[i] = src[i];
  __syncthreads();
  const int t = threadIdx.x >> 2, wq = threadIdx.x & 3;
  const int h = (t < 32) ? t : (192 + t);
  float sr, cr;
  sincosf(-TWO_PI * (float)h / 256.0f, &sr, &cr);
  float pc = (yh && (t & 1)) ? -1.f : 1.f, ps = 0.f;
  float ar[8], ai[8];
#pragma unroll
  for (int k = 0; k < 8; ++k) { ar[k] = 0.f; ai[k] = 0.f; }
  const float* zb = (const float*)zs + wq * 16;
#pragma unroll 2
  for (int y = 0; y < 128; ++y) {
    const float4* zf = (const float4*)(zb + y * 64);
#pragma unroll
    for (int k = 0; k < 4; ++k) {
      const float4 q = zf[k];
      ar[2 * k]     = fmaf(q.x, pc, fmaf(-q.y, ps, ar[2 * k]));
      ai[2 * k]     = fmaf(q.x, ps, fmaf( q.y, pc, ai[2 * k]));
      ar[2 * k + 1] = fmaf(q.z, pc, fmaf(-q.w, ps, ar[2 * k + 1]));
      ai[2 * k + 1] = fmaf(q.z, ps, fmaf( q.w, pc, ai[2 * k + 1]));
    }
    const float tn = fmaf(pc, cr, -ps * sr);
    ps = fmaf(pc, sr, ps * cr);
    pc = tn;
  }
  float4* dst = (float4*)(z2p + (long)yh * 524288 + (long)bc * 2048 + t * 32 + wq * 8);
#pragma unroll
  for (int k = 0; k < 4; ++k)
    dst[k] = make_float4(ar[2 * k], ai[2 * k], ar[2 * k + 1], ai[2 * k + 1]);
}

// kC: 1024 blocks; block = 16 modes (same b,t; 16 w). Sums z2a+z2b at load.
__global__ __launch_bounds__(256) void kC(const float2* __restrict__ z2a,
                                          const float2* __restrict__ z2b,
                                          const float2* __restrict__ kp,
                                          float2* __restrict__ g) {
  __shared__ float2 z2s[16 * 33];
  __shared__ float2 fk[16 * 33];
  __shared__ float2 tw[32];
  const int tid = threadIdx.x;
  if (tid < 32) {
    float s, c;
    sincosf(-TWO_PI * (float)tid / 32.0f, &s, &c);
    tw[tid] = make_float2(c, s);
  }
  const int m0 = blockIdx.x * 16;
  const int b = m0 >> 11;
  const int twi = m0 & 2047;
  const int t = twi >> 5;
  const int w0 = twi & 31;
  const int s_ = t >> 5, tm = t & 31;
  for (int i = tid; i < 512; i += 256) {
    const int ci = i >> 4, wj = i & 15;
    const long idx = ((long)(b * 32 + ci)) * 2048 + t * 32 + w0 + wj;
    const float2 va = z2a[idx], vb = z2b[idx];
    z2s[wj * 33 + ci] = make_float2(va.x + vb.x, va.y + vb.y);
  }
  __syncthreads();
  const int m = tid & 15;
  const int p = tid >> 4;
  const int cf0 = 2 * p, cf1 = 2 * p + 1;
  {
    float f0r = 0, f0i = 0, f1r = 0, f1i = 0;
    int i0 = 0, i1 = 0;
#pragma unroll 8
    for (int ci = 0; ci < 32; ++ci) {
      const float2 z = z2s[m * 33 + ci];
      const float2 t0 = tw[i0]; i0 = (i0 + cf0) & 31;
      const float2 t1 = tw[i1]; i1 = (i1 + cf1) & 31;
      f0r = fmaf(z.x, t0.x, fmaf(-z.y, t0.y, f0r));
      f0i = fmaf(z.x, t0.y, fmaf( z.y, t0.x, f0i));
      f1r = fmaf(z.x, t1.x, fmaf(-z.y, t1.y, f1r));
      f1i = fmaf(z.x, t1.y, fmaf( z.y, t1.x, f1i));
    }
    const float2 k0 = kp[((s_ * 32 + cf0) * 32 + tm) * 32 + w0 + m];
    const float2 k1 = kp[((s_ * 32 + cf1) * 32 + tm) * 32 + w0 + m];
    fk[m * 33 + cf0] = make_float2(f0r * k0.x - f0i * k0.y, f0r * k0.y + f0i * k0.x);
    fk[m * 33 + cf1] = make_float2(f1r * k1.x - f1i * k1.y, f1r * k1.y + f1i * k1.x);
  }
  __syncthreads();
  {
    float g0r = 0, g0i = 0, g1r = 0, g1i = 0;
    int i0 = 0, i1 = 0;
    const int co0 = 2 * p, co1 = 2 * p + 1;
#pragma unroll 8
    for (int cf = 0; cf < 32; ++cf) {
      const float2 f = fk[m * 33 + cf];
      const float2 t0 = tw[i0]; i0 = (i0 + co0) & 31;
      const float2 t1 = tw[i1]; i1 = (i1 + co1) & 31;
      g0r = fmaf(f.x, t0.x, fmaf( f.y, t0.y, g0r));
      g0i = fmaf(f.y, t0.x, fmaf(-f.x, t0.y, g0i));
      g1r = fmaf(f.x, t1.x, fmaf( f.y, t1.y, g1r));
      g1i = fmaf(f.y, t1.x, fmaf(-f.x, t1.y, g1i));
    }
    const float SC = 1.0f / 8192.0f;
    g[((long)(b * 32 + co0)) * 2048 + t * 32 + w0 + m] = make_float2(g0r * SC, g0i * SC);
    g[((long)(b * 32 + co1)) * 2048 + t * 32 + w0 + m] = make_float2(g1r * SC, g1i * SC);
  }
}

// kD: 512 blocks = (bc, yh). Thread = (yl=tid>>1, wh=tid&1): 16 w per thread.
__global__ __launch_bounds__(256) void kD(const float2* __restrict__ g,
                                          float2* __restrict__ tb) {
  __shared__ float2 gs[64 * 32];  // 16 KB
  const int bc = blockIdx.x >> 1, yh = blockIdx.x & 1;
  const float2* src = g + (long)bc * 2048;
  for (int i = threadIdx.x; i < 2048; i += 256) gs[i] = src[i];
  __syncthreads();
  const int yl = threadIdx.x >> 1, wh = threadIdx.x & 1;
  const int y = yh * 128 + yl;
  float s1, c1;
  sincosf(TWO_PI * (float)y / 256.0f, &s1, &c1);  // step e^{+2pi i y/256}
  float Tr[16], Ti[16];
#pragma unroll
  for (int k = 0; k < 16; ++k) { Tr[k] = 0.f; Ti[k] = 0.f; }
  float pc = 1.f, ps = 0.f;
  const float* gb = (const float*)gs + wh * 32;
  for (int t = 0; t < 64; ++t) {
    if (t == 32) {
      float s2, c2;
      sincosf(TWO_PI * (float)((224 * y) & 255) / 256.0f, &s2, &c2);
      pc = c2; ps = s2;
    }
    const float4* gf = (const float4*)(gb + t * 64);
#pragma unroll
    for (int k = 0; k < 8; ++k) {
      const float4 q = gf[k];
      Tr[2 * k]     = fmaf(q.x, pc, fmaf(-q.y, ps, Tr[2 * k]));
      Ti[2 * k]     = fmaf(q.x, ps, fmaf( q.y, pc, Ti[2 * k]));
      Tr[2 * k + 1] = fmaf(q.z, pc, fmaf(-q.w, ps, Tr[2 * k + 1]));
      Ti[2 * k + 1] = fmaf(q.z, ps, fmaf( q.w, pc, Ti[2 * k + 1]));
    }
    const float tn = fmaf(pc, c1, -ps * s1);
    ps = fmaf(pc, s1, ps * c1);
    pc = tn;
  }
  float4* dst = (float4*)(tb + (long)bc * 8192 + y * 32 + wh * 16);
#pragma unroll
  for (int k = 0; k < 8; ++k)
    dst[k] = make_float4(Tr[2 * k], Ti[2 * k], Tr[2 * k + 1], Ti[2 * k + 1]);
}

// kE: 2048 blocks; block = 32 rows. Thread = (xq=tid&31 -> x in {xq+32m, m<4},
// rh=tid>>5 -> rows 4rh..4rh+3). 4 x-phasors per thread (steps related by
// x e^{i pi m/4}) reuse each tst read for 4 x-values -> LDS instr / 4.
// out(x)=C-S, out((256-x)&255)=C+S; col 128 via divergent tail (first 32 lanes).
// T staged [w][r] stride 34 float2, scale folded (1/256 for w=0, 2/256 else).
__global__ __launch_bounds__(256) void kE(const float2* __restrict__ tb,
                                          float* __restrict__ out) {
  __shared__ float2 tst[32 * 34];  // 8.5 KB
  const long row0 = (long)blockIdx.x * 32;
  const int tid = threadIdx.x;
  for (int i = tid; i < 1024; i += 256) {
    const int w = i & 31, r = i >> 5;
    const float2 v = tb[(row0 + r) * 32 + w];
    const float sc = w ? (2.0f / 256.0f) : (1.0f / 256.0f);
    tst[w * 34 + r] = make_float2(v.x * sc, v.y * sc);
  }
  __syncthreads();
  const int xq = tid & 31;  // x = xq + 32*m
  const int rh = tid >> 5;  // rows rh*4 .. rh*4+3
  float sb, cb;
  sincosf(TWO_PI * (float)xq / 256.0f, &sb, &cb);
  // step_m = (cb + i sb) * e^{i pi m / 4}
  const float RT = 0.70710678118654752440f;
  const float stc1 = RT * (cb - sb), sts1 = RT * (cb + sb);
  const float stc[4] = {cb, stc1, -sb, -sts1};
  const float sts[4] = {sb, sts1, cb, stc1};
  float C[4][4], S[4][4];
#pragma unroll
  for (int m = 0; m < 4; ++m)
#pragma unroll
    for (int j = 0; j < 4; ++j) { C[m][j] = 0.f; S[m][j] = 0.f; }
  float pc[4] = {1.f, 1.f, 1.f, 1.f}, ps[4] = {0.f, 0.f, 0.f, 0.f};
  const float* tbse = (const float*)tst + rh * 8;
#pragma unroll 2
  for (int w = 0; w < 32; ++w) {
    const float4 q0 = *(const float4*)(tbse + w * 68);      // rows 4rh, 4rh+1
    const float4 q1 = *(const float4*)(tbse + w * 68 + 4);  // rows 4rh+2, 4rh+3
#pragma unroll
    for (int m = 0; m < 4; ++m) {
      C[m][0] = fmaf(q0.x, pc[m], C[m][0]);
      S[m][0] = fmaf(q0.y, ps[m], S[m][0]);
      C[m][1] = fmaf(q0.z, pc[m], C[m][1]);
      S[m][1] = fmaf(q0.w, ps[m], S[m][1]);
      C[m][2] = fmaf(q1.x, pc[m], C[m][2]);
      S[m][2] = fmaf(q1.y, ps[m], S[m][2]);
      C[m][3] = fmaf(q1.z, pc[m], C[m][3]);
      S[m][3] = fmaf(q1.w, ps[m], S[m][3]);
      const float tn = fmaf(pc[m], stc[m], -ps[m] * sts[m]);
      ps[m] = fmaf(pc[m], sts[m], ps[m] * stc[m]);
      pc[m] = tn;
    }
  }
#pragma unroll
  for (int m = 0; m < 4; ++m) {
    const int xx = xq + 32 * m;
#pragma unroll
    for (int j = 0; j < 4; ++j) {
      const long row = row0 + rh * 4 + j;
      out[row * 256 + xx] = C[m][j] - S[m][j];
      out[row * 256 + ((256 - xx) & 255)] = C[m][j] + S[m][j];
    }
  }
  if (tid < 32) {  // column x=128: sum (-1)^w a_w
    float ae = 0.f, ao = 0.f;
#pragma unroll
    for (int k = 0; k < 16; ++k) {
      ae += tst[(2 * k) * 34 + tid].x;
      ao += tst[(2 * k + 1) * 34 + tid].x;
    }
    out[(row0 + tid) * 256 + 128] = ae - ao;
  }
}

extern "C" void kernel_launch(void* const* d_in, const int* in_sizes, int n_in,
                              void* d_out, int out_size, void* d_ws, size_t ws_size,
                              hipStream_t stream) {
  const float* x = (const float*)d_in[0];
  const float* kin = (const float*)d_in[1];
  const float* rp = (const float*)d_in[2];
  float* out = (float*)d_out;
  char* ws = (char*)d_ws;

  float2* z1  = (float2*)(ws);                   // 0..16M
  float2* z2a = (float2*)(ws + (16ull << 20));   // 16..24M (z2b = z2a+524288)
  float2* kp  = (float2*)(ws + (24ull << 20));   // 24..24.5M
  float2* g   = (float2*)(ws);                   // 0..4M (over dead z1)
  float2* tb  = (float2*)(ws + (4ull << 20));    // 4..20M (over dead z1/z2a)

  kP<<<256, 256, 0, stream>>>(kin, rp, kp);
  kA<<<2048, 256, 0, stream>>>(x, z1);
  kB<<<512, 256, 0, stream>>>(z1, z2a);
  kC<<<1024, 256, 0, stream>>>(z2a, z2a + 524288, kp, g);
  kD<<<512, 256, 0, stream>>>(g, tb);
  kE<<<2048, 256, 0, stream>>>(tb, out);
}

// Round 3
// 210.316 us; speedup vs baseline: 1.0297x; 1.0036x over previous
//
#include <hip/hip_runtime.h>
#include <math.h>

// FourierKNOConv2d: x[8,32,256,256] f32, kernel[2,1,32,32,32,2] f32, r scalar.
// out[8,32,256,256] f32.
//   kP: Kp = (kr + i ki)^r                                  [2,32,32,32] c64
//   kA: Z1[row,w] = sum_x X[row,x] e^{-2pi i w x/256}, w<32  (x<->256-x symmetry)
//   kB: Z2[bc,t,w] = sum_y Z1[bc,y,w] e^{-2pi i h(t) y/256}, h(t)=t<32?t:192+t
//       (split y into two halves -> z2a + z2b, summed in kC)
//   kC: G = idft32_ch( dft32_ch(z2a+z2b) * Kp ) / 8192
//   kDE: fused kD+kE per (bc, 32-row y-group):
//        T[y,w] = sum_t G[bc,t,w] e^{+2pi i h(t) y/256}  (phase 2, in LDS)
//        out[row,x] = C(x)-S(x), out[row,256-x]=C(x)+S(x) (phase 3, x-symmetry)
// ws map (24.5 MB, stream-ordered reuse):
//   z1  @0..16M    (kA w, kB r)
//   z2a @16..20M, z2b @20..24M (kB w, kC r)
//   kp  @24..24.5M (kP w, kC r)
//   g   @0..4M     (kC w, kDE r; over dead z1)

#define TWO_PI 6.28318530717958647692f

__global__ __launch_bounds__(256) void kP(const float* __restrict__ kin,
                                          const float* __restrict__ rp,
                                          float2* __restrict__ kp) {
  const int i = blockIdx.x * 256 + threadIdx.x;  // < 65536
  const float r = rp[0];
  const float kr = kin[2 * i], ki = kin[2 * i + 1];
  const float m2 = fmaf(kr, kr, ki * ki);
  float2 o = make_float2(0.f, 0.f);
  if (m2 > 0.f) {
    const float lm = 0.5f * logf(m2);
    const float ang = atan2f(ki, kr);
    const float mag = expf(r * lm);
    float s, c;
    sincosf(r * ang, &s, &c);
    o = make_float2(mag * c, mag * s);
  }
  kp[i] = o;
}

// kA: 2048 blocks; block = 32 rows. LDS 32 KB via rotate-swizzle:
//   word idx(x,r) = x*32 + ((r + 4x) & 31)
// b128 quads (r multiple of 4) stay contiguous under the rotate.
// Staging now writes whole quads (ds_write_b128): thread = (xl=tid&31,
// rq=tid>>5) owns rows 4rq..4rq+3 for columns xl+32cb — write is
// data-bound (1KB/wave), no 8-way b32 conflicts.
// Thread (main) = (w=tid&31, rq=tid>>5): 1 freq x 4 rows; 8-batch unrolled
// x-loop with precomputed swizzle offsets uo[8].
__global__ __launch_bounds__(256) void kA(const float* __restrict__ x,
                                          float2* __restrict__ z1) {
  __shared__ float xs[8192];  // 32 KB
  const int tid = threadIdx.x;
  const long row0 = (long)blockIdx.x * 32;
  const float* xg = x + row0 * 256;
  {
    const int xl = tid & 31, rq = tid >> 5;  // rows 4rq..4rq+3
    const float* xgr = xg + rq * 4 * 256 + xl;
#pragma unroll
    for (int cb = 0; cb < 8; ++cb) {
      const int xc = xl + 32 * cb;
      const float4 v = make_float4(xgr[32 * cb], xgr[32 * cb + 256],
                                   xgr[32 * cb + 512], xgr[32 * cb + 768]);
      *(float4*)(xs + xc * 32 + 4 * ((rq + xc) & 7)) = v;
    }
  }
  __syncthreads();
  for (int i = tid; i < 127 * 32; i += 256) {
    const int xi = 1 + (i >> 5), r = i & 31;
    const int ai = (xi << 5) + ((r + 4 * xi) & 31);
    const int bi = ((256 - xi) << 5) + ((r - 4 * xi) & 31);
    const float a = xs[ai], b = xs[bi];
    xs[ai] = a + b;          // u
    xs[bi] = a - b;          // v
  }
  __syncthreads();
  const int w = tid & 31;
  const int r0 = (tid >> 5) << 2;  // rows r0..r0+3
  int uo[8];                       // byte offsets of swizzled quad, period 8 in x
#pragma unroll
  for (int j = 0; j < 8; ++j) uo[j] = ((r0 + 4 * j) & 31) << 2;
  // edge terms: Re += X(0) + (-1)^w X(128)   (idx(0,r)=r, idx(128,r)=4096+r)
  const float sgn = (w & 1) ? -1.f : 1.f;
  const float4 x0 = *(const float4*)(xs + r0);
  const float4 x128 = *(const float4*)(xs + (128 << 5) + r0);
  float Cr0 = fmaf(sgn, x128.x, x0.x), Cr1 = fmaf(sgn, x128.y, x0.y);
  float Cr2 = fmaf(sgn, x128.z, x0.z), Cr3 = fmaf(sgn, x128.w, x0.w);
  float Ci0 = 0, Ci1 = 0, Ci2 = 0, Ci3 = 0;
  float s1, c1;
  sincosf(TWO_PI * (float)w / 256.0f, &s1, &c1);
  float pc = c1, ps = s1;  // phasor at x=1 (positive angle; sign applied on Im)
  const char* const xsb = (const char*)xs;
#define KA_BODY(UPTR, VPTR)                                        \
  {                                                                \
    const float4 u = *(const float4*)(UPTR);                       \
    const float4 v = *(const float4*)(VPTR);                       \
    Cr0 = fmaf(u.x, pc, Cr0); Ci0 = fmaf(-v.x, ps, Ci0);           \
    Cr1 = fmaf(u.y, pc, Cr1); Ci1 = fmaf(-v.y, ps, Ci1);           \
    Cr2 = fmaf(u.z, pc, Cr2); Ci2 = fmaf(-v.z, ps, Ci2);           \
    Cr3 = fmaf(u.w, pc, Cr3); Ci3 = fmaf(-v.w, ps, Ci3);           \
    const float tn = fmaf(pc, c1, -ps * s1);                       \
    ps = fmaf(pc, s1, ps * c1);                                    \
    pc = tn;                                                       \
  }
  {  // batch 0: xx = 1..7  (v at x'=256-j -> base 249*128 + (7-j)*128)
    const char* ub = xsb;
    const char* vb = xsb + 249 * 128;
#pragma unroll
    for (int j = 1; j < 8; ++j)
      KA_BODY(ub + j * 128 + uo[j], vb + (7 - j) * 128 + uo[8 - j])
  }
  for (int xb = 8; xb <= 120; xb += 8) {  // xx = 8..127
    const char* ub = xsb + xb * 128;
    const char* vb = xsb + (249 - xb) * 128;
#pragma unroll
    for (int j = 0; j < 8; ++j)
      KA_BODY(ub + j * 128 + uo[j], vb + (7 - j) * 128 + uo[(8 - j) & 7])
  }
#undef KA_BODY
  float2* o = z1 + (row0 + r0) * 32 + w;
  o[0]  = make_float2(Cr0, Ci0);
  o[32] = make_float2(Cr1, Ci1);
  o[64] = make_float2(Cr2, Ci2);
  o[96] = make_float2(Cr3, Ci3);
}

// kB: 512 blocks = (bc, yh). Thread = (t=tid>>2, wq=tid&3): 8 w per thread.
// Partial over 128 y -> z2p[yh]. Phasor start (-1)^(h*yh), step e^{-2pi i h/256}.
__global__ __launch_bounds__(256) void kB(const float2* __restrict__ z1,
                                          float2* __restrict__ z2p) {
  __shared__ float2 zs[128 * 32];  // 32 KB, [y][w]
  const int bc = blockIdx.x >> 1, yh = blockIdx.x & 1;
  const float2* src = z1 + (long)bc * 8192 + yh * 4096;
  for (int i = threadIdx.x; i < 4096; i += 256) zs[i] = src[i];
  __syncthreads();
  const int t = threadIdx.x >> 2, wq = threadIdx.x & 3;
  const int h = (t < 32) ? t : (192 + t);
  float sr, cr;
  sincosf(-TWO_PI * (float)h / 256.0f, &sr, &cr);
  float pc = (yh && (t & 1)) ? -1.f : 1.f, ps = 0.f;
  float ar[8], ai[8];
#pragma unroll
  for (int k = 0; k < 8; ++k) { ar[k] = 0.f; ai[k] = 0.f; }
  const float* zb = (const float*)zs + wq * 16;
#pragma unroll 2
  for (int y = 0; y < 128; ++y) {
    const float4* zf = (const float4*)(zb + y * 64);
#pragma unroll
    for (int k = 0; k < 4; ++k) {
      const float4 q = zf[k];
      ar[2 * k]     = fmaf(q.x, pc, fmaf(-q.y, ps, ar[2 * k]));
      ai[2 * k]     = fmaf(q.x, ps, fmaf( q.y, pc, ai[2 * k]));
      ar[2 * k + 1] = fmaf(q.z, pc, fmaf(-q.w, ps, ar[2 * k + 1]));
      ai[2 * k + 1] = fmaf(q.z, ps, fmaf( q.w, pc, ai[2 * k + 1]));
    }
    const float tn = fmaf(pc, cr, -ps * sr);
    ps = fmaf(pc, sr, ps * cr);
    pc = tn;
  }
  float4* dst = (float4*)(z2p + (long)yh * 524288 + (long)bc * 2048 + t * 32 + wq * 8);
#pragma unroll
  for (int k = 0; k < 4; ++k)
    dst[k] = make_float4(ar[2 * k], ai[2 * k], ar[2 * k + 1], ai[2 * k + 1]);
}

// kC: 1024 blocks; block = 16 modes (same b,t; 16 w). Sums z2a+z2b at load.
__global__ __launch_bounds__(256) void kC(const float2* __restrict__ z2a,
                                          const float2* __restrict__ z2b,
                                          const float2* __restrict__ kp,
                                          float2* __restrict__ g) {
  __shared__ float2 z2s[16 * 33];
  __shared__ float2 fk[16 * 33];
  __shared__ float2 tw[32];
  const int tid = threadIdx.x;
  if (tid < 32) {
    float s, c;
    sincosf(-TWO_PI * (float)tid / 32.0f, &s, &c);
    tw[tid] = make_float2(c, s);
  }
  const int m0 = blockIdx.x * 16;
  const int b = m0 >> 11;
  const int twi = m0 & 2047;
  const int t = twi >> 5;
  const int w0 = twi & 31;
  const int s_ = t >> 5, tm = t & 31;
  for (int i = tid; i < 512; i += 256) {
    const int ci = i >> 4, wj = i & 15;
    const long idx = ((long)(b * 32 + ci)) * 2048 + t * 32 + w0 + wj;
    const float2 va = z2a[idx], vb = z2b[idx];
    z2s[wj * 33 + ci] = make_float2(va.x + vb.x, va.y + vb.y);
  }
  __syncthreads();
  const int m = tid & 15;
  const int p = tid >> 4;
  const int cf0 = 2 * p, cf1 = 2 * p + 1;
  {
    float f0r = 0, f0i = 0, f1r = 0, f1i = 0;
    int i0 = 0, i1 = 0;
#pragma unroll 8
    for (int ci = 0; ci < 32; ++ci) {
      const float2 z = z2s[m * 33 + ci];
      const float2 t0 = tw[i0]; i0 = (i0 + cf0) & 31;
      const float2 t1 = tw[i1]; i1 = (i1 + cf1) & 31;
      f0r = fmaf(z.x, t0.x, fmaf(-z.y, t0.y, f0r));
      f0i = fmaf(z.x, t0.y, fmaf( z.y, t0.x, f0i));
      f1r = fmaf(z.x, t1.x, fmaf(-z.y, t1.y, f1r));
      f1i = fmaf(z.x, t1.y, fmaf( z.y, t1.x, f1i));
    }
    const float2 k0 = kp[((s_ * 32 + cf0) * 32 + tm) * 32 + w0 + m];
    const float2 k1 = kp[((s_ * 32 + cf1) * 32 + tm) * 32 + w0 + m];
    fk[m * 33 + cf0] = make_float2(f0r * k0.x - f0i * k0.y, f0r * k0.y + f0i * k0.x);
    fk[m * 33 + cf1] = make_float2(f1r * k1.x - f1i * k1.y, f1r * k1.y + f1i * k1.x);
  }
  __syncthreads();
  {
    float g0r = 0, g0i = 0, g1r = 0, g1i = 0;
    int i0 = 0, i1 = 0;
    const int co0 = 2 * p, co1 = 2 * p + 1;
#pragma unroll 8
    for (int cf = 0; cf < 32; ++cf) {
      const float2 f = fk[m * 33 + cf];
      const float2 t0 = tw[i0]; i0 = (i0 + co0) & 31;
      const float2 t1 = tw[i1]; i1 = (i1 + co1) & 31;
      g0r = fmaf(f.x, t0.x, fmaf( f.y, t0.y, g0r));
      g0i = fmaf(f.y, t0.x, fmaf(-f.x, t0.y, g0i));
      g1r = fmaf(f.x, t1.x, fmaf( f.y, t1.y, g1r));
      g1i = fmaf(f.y, t1.x, fmaf(-f.x, t1.y, g1i));
    }
    const float SC = 1.0f / 8192.0f;
    g[((long)(b * 32 + co0)) * 2048 + t * 32 + w0 + m] = make_float2(g0r * SC, g0i * SC);
    g[((long)(b * 32 + co1)) * 2048 + t * 32 + w0 + m] = make_float2(g1r * SC, g1i * SC);
  }
}

// kDE: fused kD+kE. 2048 blocks = (bc = bid>>3, yq = bid&7); 32 rows/block.
// Phase 1: g[bc] (16 KB) -> LDS.
// Phase 2 (kD math, 32 y x 32 w): thread = (y5=tid>>3, wq=tid&7): 4 w per
//   thread over 64 t; phasor step e^{+2pi i y/256}, reset at t=32 to
//   e^{+2pi i 224y/256}. Result scaled (1/256 w=0, 2/256 else) into
//   tst[w][y] (stride 34 float2) — kE's layout.
// Phase 3 (kE math): thread = (xq=tid&31 -> x in {xq+32m}, rh=tid>>5 ->
//   rows 4rh..4rh+3); 4 x-phasors (steps related by x e^{i pi m/4}).
//   out(x)=C-S, out((256-x)&255)=C+S; col 128 via first-32-lane tail.
__global__ __launch_bounds__(256) void kDE(const float2* __restrict__ g,
                                           float* __restrict__ out) {
  __shared__ float2 gs[2048];     // 16 KB
  __shared__ float2 tst[32 * 34]; // 8.5 KB
  const int tid = threadIdx.x;
  const int bc = blockIdx.x >> 3, yq = blockIdx.x & 7;
  const float2* src = g + (long)bc * 2048;
  for (int i = tid; i < 2048; i += 256) gs[i] = src[i];
  __syncthreads();
  {  // phase 2
    const int y5 = tid >> 3, wq = tid & 7;
    const int y = yq * 32 + y5;
    float s1, c1;
    sincosf(TWO_PI * (float)y / 256.0f, &s1, &c1);
    float Tr[4], Ti[4];
#pragma unroll
    for (int k = 0; k < 4; ++k) { Tr[k] = 0.f; Ti[k] = 0.f; }
    float pc = 1.f, ps = 0.f;
    const float* gb = (const float*)gs + wq * 8;
    for (int t = 0; t < 64; ++t) {
      if (t == 32) {
        float s2, c2;
        sincosf(TWO_PI * (float)((224 * y) & 255) / 256.0f, &s2, &c2);
        pc = c2; ps = s2;
      }
      const float4* gf = (const float4*)(gb + t * 64);
      const float4 qa = gf[0], qb = gf[1];
      Tr[0] = fmaf(qa.x, pc, fmaf(-qa.y, ps, Tr[0]));
      Ti[0] = fmaf(qa.x, ps, fmaf( qa.y, pc, Ti[0]));
      Tr[1] = fmaf(qa.z, pc, fmaf(-qa.w, ps, Tr[1]));
      Ti[1] = fmaf(qa.z, ps, fmaf( qa.w, pc, Ti[1]));
      Tr[2] = fmaf(qb.x, pc, fmaf(-qb.y, ps, Tr[2]));
      Ti[2] = fmaf(qb.x, ps, fmaf( qb.y, pc, Ti[2]));
      Tr[3] = fmaf(qb.z, pc, fmaf(-qb.w, ps, Tr[3]));
      Ti[3] = fmaf(qb.z, ps, fmaf( qb.w, pc, Ti[3]));
      const float tn = fmaf(pc, c1, -ps * s1);
      ps = fmaf(pc, s1, ps * c1);
      pc = tn;
    }
#pragma unroll
    for (int k = 0; k < 4; ++k) {
      const int w = wq * 4 + k;
      const float sc = w ? (2.0f / 256.0f) : (1.0f / 256.0f);
      tst[w * 34 + y5] = make_float2(Tr[k] * sc, Ti[k] * sc);
    }
  }
  __syncthreads();
  {  // phase 3
    const int xq = tid & 31;  // x = xq + 32*m
    const int rh = tid >> 5;  // rows rh*4 .. rh*4+3
    float sb, cb;
    sincosf(TWO_PI * (float)xq / 256.0f, &sb, &cb);
    const float RT = 0.70710678118654752440f;
    const float stc1 = RT * (cb - sb), sts1 = RT * (cb + sb);
    const float stc[4] = {cb, stc1, -sb, -sts1};
    const float sts[4] = {sb, sts1, cb, stc1};
    float C[4][4], S[4][4];
#pragma unroll
    for (int m = 0; m < 4; ++m)
#pragma unroll
      for (int j = 0; j < 4; ++j) { C[m][j] = 0.f; S[m][j] = 0.f; }
    float pc[4] = {1.f, 1.f, 1.f, 1.f}, ps[4] = {0.f, 0.f, 0.f, 0.f};
    const float* tbse = (const float*)tst + rh * 8;
#pragma unroll 2
    for (int w = 0; w < 32; ++w) {
      const float4 q0 = *(const float4*)(tbse + w * 68);      // rows 4rh, 4rh+1
      const float4 q1 = *(const float4*)(tbse + w * 68 + 4);  // rows 4rh+2, 4rh+3
#pragma unroll
      for (int m = 0; m < 4; ++m) {
        C[m][0] = fmaf(q0.x, pc[m], C[m][0]);
        S[m][0] = fmaf(q0.y, ps[m], S[m][0]);
        C[m][1] = fmaf(q0.z, pc[m], C[m][1]);
        S[m][1] = fmaf(q0.w, ps[m], S[m][1]);
        C[m][2] = fmaf(q1.x, pc[m], C[m][2]);
        S[m][2] = fmaf(q1.y, ps[m], S[m][2]);
        C[m][3] = fmaf(q1.z, pc[m], C[m][3]);
        S[m][3] = fmaf(q1.w, ps[m], S[m][3]);
        const float tn = fmaf(pc[m], stc[m], -ps[m] * sts[m]);
        ps[m] = fmaf(pc[m], sts[m], ps[m] * stc[m]);
        pc[m] = tn;
      }
    }
    const long rbase = (long)bc * 256 + yq * 32;
#pragma unroll
    for (int m = 0; m < 4; ++m) {
      const int xx = xq + 32 * m;
#pragma unroll
      for (int j = 0; j < 4; ++j) {
        const long row = rbase + rh * 4 + j;
        out[row * 256 + xx] = C[m][j] - S[m][j];
        out[row * 256 + ((256 - xx) & 255)] = C[m][j] + S[m][j];
      }
    }
    if (tid < 32) {  // column x=128: sum (-1)^w a_w
      float ae = 0.f, ao = 0.f;
#pragma unroll
      for (int k = 0; k < 16; ++k) {
        ae += tst[(2 * k) * 34 + tid].x;
        ao += tst[(2 * k + 1) * 34 + tid].x;
      }
      out[(rbase + tid) * 256 + 128] = ae - ao;
    }
  }
}

extern "C" void kernel_launch(void* const* d_in, const int* in_sizes, int n_in,
                              void* d_out, int out_size, void* d_ws, size_t ws_size,
                              hipStream_t stream) {
  const float* x = (const float*)d_in[0];
  const float* kin = (const float*)d_in[1];
  const float* rp = (const float*)d_in[2];
  float* out = (float*)d_out;
  char* ws = (char*)d_ws;

  float2* z1  = (float2*)(ws);                   // 0..16M
  float2* z2a = (float2*)(ws + (16ull << 20));   // 16..24M (z2b = z2a+524288)
  float2* kp  = (float2*)(ws + (24ull << 20));   // 24..24.5M
  float2* g   = (float2*)(ws);                   // 0..4M (over dead z1)

  kP<<<256, 256, 0, stream>>>(kin, rp, kp);
  kA<<<2048, 256, 0, stream>>>(x, z1);
  kB<<<512, 256, 0, stream>>>(z1, z2a);
  kC<<<1024, 256, 0, stream>>>(z2a, z2a + 524288, kp, g);
  kDE<<<2048, 256, 0, stream>>>(g, out);
}